// Round 2
// baseline (537.815 us; speedup 1.0000x reference)
//
#include <hip/hip_runtime.h>

// Problem constants (B,V,T,H,W) = (32, 8, 2, 192, 288)
#define D        16        // V*T
#define NPAIR    136       // D*(D+1)/2 upper-triangle Gram entries
#define NVALS    152       // NPAIR + D row sums
#define HW       55296     // H*W
#define HW2      27648     // HW/2 (float2 columns per batch-plane)
#define BSTRIDE  884736    // V*T*H*W (batch stride in floats)
#define NTOT     1769472   // B*H*W = N
#define NCOL2    884736    // NTOT/2 float2-columns
#define G        1728      // gram blocks (NCOL2/CPB; 27648 % 512 == 0 -> one batch per block)
#define CPB      512       // float2-columns per block
#define ITERS    8         // CPB / 64

__device__ __forceinline__ float wave_reduce(float x) {
    x += __shfl_down(x, 32);
    x += __shfl_down(x, 16);
    x += __shfl_down(x, 8);
    x += __shfl_down(x, 4);
    x += __shfl_down(x, 2);
    x += __shfl_down(x, 1);
    return x;
}

// One wave handles pair-set SET = tri-indices [34*SET, 34*SET+34) and row
// sums for d in [4*SET, 4*SET+4). All 4 waves of a block sweep the SAME
// columns -> redundant global reads hit L1/L2; compiler DCEs the r[d] loads
// a set doesn't touch (set 3 only loads d=8..15).
template<int SET>
__device__ __forceinline__ void gram_run(const float* __restrict__ yt,
                                         const float* __restrict__ yp,
                                         float* __restrict__ part,
                                         int blk, int lane) {
    float acc[34];
    float sums[4];
#pragma unroll
    for (int j = 0; j < 34; ++j) acc[j] = 0.0f;
#pragma unroll
    for (int j = 0; j < 4; ++j) sums[j] = 0.0f;

    const int colbase = blk * CPB;          // float2-column index
    const int b  = colbase / HW2;           // whole block inside one batch b
    const int k0 = colbase - b * HW2;
    const float* bt = yt + (size_t)b * BSTRIDE + 2 * k0;
    const float* bp = yp + (size_t)b * BSTRIDE + 2 * k0;

    for (int it = 0; it < ITERS; ++it) {
        const int off = (it * 64 + lane) * 2;
        float2 r[D];
#pragma unroll
        for (int d = 0; d < D; ++d) {
            const float2 a = *reinterpret_cast<const float2*>(bt + d * HW + off);
            const float2 p = *reinterpret_cast<const float2*>(bp + d * HW + off);
            r[d] = make_float2(a.x - p.x, a.y - p.y);
        }
        int idx = 0;
#pragma unroll
        for (int d = 0; d < D; ++d) {
#pragma unroll
            for (int e = d; e < D; ++e, ++idx) {
                if (idx >= SET * 34 && idx < SET * 34 + 34) {   // constexpr-folded
                    acc[idx - SET * 34] += r[d].x * r[e].x;
                    acc[idx - SET * 34] += r[d].y * r[e].y;
                }
            }
        }
#pragma unroll
        for (int d = 0; d < 4; ++d)
            sums[d] += r[SET * 4 + d].x + r[SET * 4 + d].y;
    }

    // Per-wave reduction; sets are disjoint so no cross-wave work, no LDS.
#pragma unroll
    for (int j = 0; j < 34; ++j) {
        const float v = wave_reduce(acc[j]);
        if (lane == 0) part[(SET * 38 + j) * G + blk] = v;
    }
#pragma unroll
    for (int j = 0; j < 4; ++j) {
        const float v = wave_reduce(sums[j]);
        if (lane == 0) part[(SET * 38 + 34 + j) * G + blk] = v;
    }
}

__global__ __launch_bounds__(256, 4)
void gram_partial(const float* __restrict__ yt, const float* __restrict__ yp,
                  float* __restrict__ part) {
    const int lane = threadIdx.x & 63;
    const int wid  = threadIdx.x >> 6;
    switch (wid) {
        case 0:  gram_run<0>(yt, yp, part, blockIdx.x, lane); break;
        case 1:  gram_run<1>(yt, yp, part, blockIdx.x, lane); break;
        case 2:  gram_run<2>(yt, yp, part, blockIdx.x, lane); break;
        default: gram_run<3>(yt, yp, part, blockIdx.x, lane); break;
    }
}

__device__ __forceinline__ int tri_idx(int d, int e) {
    // d <= e required
    return d * D - (d * (d - 1)) / 2 + (e - d);
}

// Pass 2 (single block, 256 threads): reduce partials, build cov, invert
// 16x16 via cooperative Gauss-Jordan, emit (1/N) * sum(P .* S).
__global__ void finalize_kernel(const float* __restrict__ part,
                                float* __restrict__ out) {
    __shared__ float Stri[NPAIR];
    __shared__ float Ssum[D];
    __shared__ float A[D][2 * D + 1];   // [cov | I], padded row

    const int tid  = threadIdx.x;
    const int lane = tid & 63;
    const int wv   = tid >> 6;

    // 1) Reduce G block-partials per value: one wave per value row.
    for (int vi = wv; vi < NVALS; vi += 4) {
        float s = 0.0f;
#pragma unroll
        for (int j = 0; j < G / 64; ++j)
            s += part[vi * G + j * 64 + lane];
        s = wave_reduce(s);
        if (lane == 0) {
            const int set = vi / 38;
            const int i   = vi - set * 38;
            if (i < 34) Stri[set * 34 + i]       = s;
            else        Ssum[set * 4 + (i - 34)] = s;
        }
    }
    __syncthreads();

    // 2) Augmented matrix [cov | I]
    {
        const int d = tid >> 4, e = tid & 15;
        const int lo = d < e ? d : e, hi = d < e ? e : d;
        const float invN = 1.0f / (float)NTOT;
        const float cov = (Stri[tri_idx(lo, hi)] -
                           Ssum[d] * Ssum[e] * invN) /
                          (float)(NTOT - 1);
        A[d][e]     = cov;
        A[d][D + e] = (d == e) ? 1.0f : 0.0f;
    }
    __syncthreads();

    // 3) Gauss-Jordan (no pivoting; cov ~ 0.01*I, well-conditioned).
    const int r0 = tid >> 5;   // 0..7
    const int c0 = tid & 31;   // 0..31
    const int r1 = r0 + 8;
    for (int k = 0; k < D; ++k) {
        const float pivinv = 1.0f / A[k][k];
        __syncthreads();
        if (tid < 32) A[k][tid] *= pivinv;
        __syncthreads();
        const float f0 = A[r0][k];
        const float f1 = A[r1][k];
        __syncthreads();
        const float akc = A[k][c0];
        if (r0 != k) A[r0][c0] -= f0 * akc;
        if (r1 != k) A[r1][c0] -= f1 * akc;
        __syncthreads();
    }

    // 4) result = (1/N) * sum_{d,e} P[d][e] * S[d][e]
    float term;
    {
        const int d = tid >> 4, e = tid & 15;
        const int lo = d < e ? d : e, hi = d < e ? e : d;
        float p = A[d][D + e];
        const float scale = 1.0f;  // OFF_DIAGONAL_SCALE
        if (d != e) p *= scale;
        term = p * Stri[tri_idx(lo, hi)];
    }
    term = wave_reduce(term);

    __shared__ float wsum[4];
    if (lane == 0) wsum[wv] = term;
    __syncthreads();
    if (tid == 0) {
        const float tot = (wsum[0] + wsum[1]) + (wsum[2] + wsum[3]);
        out[0] = tot / (float)NTOT;
    }
}

extern "C" void kernel_launch(void* const* d_in, const int* in_sizes, int n_in,
                              void* d_out, int out_size, void* d_ws, size_t ws_size,
                              hipStream_t stream) {
    const float* y_true = (const float*)d_in[0];
    const float* y_pred = (const float*)d_in[1];
    float* out  = (float*)d_out;
    float* part = (float*)d_ws;   // needs NVALS * G * 4 = 1,050,624 bytes

    hipLaunchKernelGGL(gram_partial, dim3(G), dim3(256), 0, stream,
                       y_true, y_pred, part);
    hipLaunchKernelGGL(finalize_kernel, dim3(1), dim3(256), 0, stream,
                       part, out);
}

// Round 3
// 537.282 us; speedup vs baseline: 1.0010x; 1.0010x over previous
//
#include <hip/hip_runtime.h>

// Problem constants (B,V,T,H,W) = (32, 8, 2, 192, 288)
#define D        16        // V*T
#define NPAIR    136       // D*(D+1)/2 upper-triangle Gram entries
#define NVALS    152       // NPAIR + D row sums
#define HW       55296     // H*W
#define HW2      27648     // HW/2 (float2 columns per batch-plane)
#define BSTRIDE  884736    // V*T*H*W (batch stride in floats)
#define NTOT     1769472   // B*H*W = N
#define NCOL2    884736    // NTOT/2 float2-columns
#define CPB      512       // float2-columns per block (27648 % 512 == 0)
#define G        1728      // NCOL2 / CPB
#define ITERS    8         // CPB / 64

__device__ __forceinline__ float wave_reduce(float x) {
    x += __shfl_down(x, 32);
    x += __shfl_down(x, 16);
    x += __shfl_down(x, 8);
    x += __shfl_down(x, 4);
    x += __shfl_down(x, 2);
    x += __shfl_down(x, 1);
    return x;
}

__host__ __device__ constexpr int tri_idx(int d, int e) {
    // d <= e required
    return d * D - (d * (d - 1)) / 2 + (e - d);
}

// Wave w owns rows {2w, 2w+1, 14-2w, 15-2w}: (16-2w)+(15-2w)+(2+2w)+(1+2w)
// = 34 pairs for every w. Four separately-sized accumulator arrays with
// template-constant loop bounds -> every index is a compile-time constant
// (round-2's flat guarded nest de-unrolled and spilled acc[] to scratch).
// All 4 waves sweep the SAME 64-column window per iteration, so the
// redundant row loads (wave w reads rows 2w..15) hit L1/L2.
template<int W>
__device__ __forceinline__ void gram_wave(const float* __restrict__ yt,
                                          const float* __restrict__ yp,
                                          float* __restrict__ part,
                                          int blk, int lane) {
    constexpr int R0 = 2 * W;        // also the min row this wave touches
    constexpr int R1 = 2 * W + 1;
    constexpr int R2 = 14 - 2 * W;
    constexpr int R3 = 15 - 2 * W;

    float accA[D - R0];
    float accB[D - R1];
    float accC[D - R2];
    float accD[D - R3];
    float sA = 0.0f, sB = 0.0f, sC = 0.0f, sD = 0.0f;
#pragma unroll
    for (int j = 0; j < D - R0; ++j) accA[j] = 0.0f;
#pragma unroll
    for (int j = 0; j < D - R1; ++j) accB[j] = 0.0f;
#pragma unroll
    for (int j = 0; j < D - R2; ++j) accC[j] = 0.0f;
#pragma unroll
    for (int j = 0; j < D - R3; ++j) accD[j] = 0.0f;

    const int colbase = blk * CPB;          // float2-column index
    const int b  = colbase / HW2;           // whole block inside one batch
    const int k0 = colbase - b * HW2;
    const float* bt = yt + (size_t)b * BSTRIDE + 2 * k0;
    const float* bp = yp + (size_t)b * BSTRIDE + 2 * k0;

    for (int it = 0; it < ITERS; ++it) {
        const int off = (it * 64 + lane) * 2;
        float2 r[D];
#pragma unroll
        for (int d = R0; d < D; ++d) {
            const float2 a = *reinterpret_cast<const float2*>(bt + d * HW + off);
            const float2 p = *reinterpret_cast<const float2*>(bp + d * HW + off);
            r[d] = make_float2(a.x - p.x, a.y - p.y);
        }
#pragma unroll
        for (int e = R0; e < D; ++e)
            accA[e - R0] += r[R0].x * r[e].x + r[R0].y * r[e].y;
#pragma unroll
        for (int e = R1; e < D; ++e)
            accB[e - R1] += r[R1].x * r[e].x + r[R1].y * r[e].y;
#pragma unroll
        for (int e = R2; e < D; ++e)
            accC[e - R2] += r[R2].x * r[e].x + r[R2].y * r[e].y;
#pragma unroll
        for (int e = R3; e < D; ++e)
            accD[e - R3] += r[R3].x * r[e].x + r[R3].y * r[e].y;
        sA += r[R0].x + r[R0].y;
        sB += r[R1].x + r[R1].y;
        sC += r[R2].x + r[R2].y;
        sD += r[R3].x + r[R3].y;
    }

    // Epilogue: per-wave shuffle reduce; write directly in tri-index layout.
#pragma unroll
    for (int e = R0; e < D; ++e) {
        const float v = wave_reduce(accA[e - R0]);
        if (lane == 0) part[tri_idx(R0, e) * G + blk] = v;
    }
#pragma unroll
    for (int e = R1; e < D; ++e) {
        const float v = wave_reduce(accB[e - R1]);
        if (lane == 0) part[tri_idx(R1, e) * G + blk] = v;
    }
#pragma unroll
    for (int e = R2; e < D; ++e) {
        const float v = wave_reduce(accC[e - R2]);
        if (lane == 0) part[tri_idx(R2, e) * G + blk] = v;
    }
#pragma unroll
    for (int e = R3; e < D; ++e) {
        const float v = wave_reduce(accD[e - R3]);
        if (lane == 0) part[tri_idx(R3, e) * G + blk] = v;
    }
    {
        float v;
        v = wave_reduce(sA); if (lane == 0) part[(NPAIR + R0) * G + blk] = v;
        v = wave_reduce(sB); if (lane == 0) part[(NPAIR + R1) * G + blk] = v;
        v = wave_reduce(sC); if (lane == 0) part[(NPAIR + R2) * G + blk] = v;
        v = wave_reduce(sD); if (lane == 0) part[(NPAIR + R3) * G + blk] = v;
    }
}

__global__ __launch_bounds__(256, 4)
void gram_partial(const float* __restrict__ yt, const float* __restrict__ yp,
                  float* __restrict__ part) {
    const int lane = threadIdx.x & 63;
    const int wid  = threadIdx.x >> 6;
    switch (wid) {
        case 0:  gram_wave<0>(yt, yp, part, blockIdx.x, lane); break;
        case 1:  gram_wave<1>(yt, yp, part, blockIdx.x, lane); break;
        case 2:  gram_wave<2>(yt, yp, part, blockIdx.x, lane); break;
        default: gram_wave<3>(yt, yp, part, blockIdx.x, lane); break;
    }
}

// Pass 2 (single block, 256 threads): reduce partials, build cov, invert
// 16x16 via cooperative Gauss-Jordan, emit (1/N) * sum(P .* S).
__global__ void finalize_kernel(const float* __restrict__ part,
                                float* __restrict__ out) {
    __shared__ float Stri[NPAIR];
    __shared__ float Ssum[D];
    __shared__ float A[D][2 * D + 1];   // [cov | I], padded row

    const int tid  = threadIdx.x;
    const int lane = tid & 63;
    const int wv   = tid >> 6;

    // 1) Reduce G block-partials per value: one wave per value row.
    for (int vi = wv; vi < NVALS; vi += 4) {
        float s = 0.0f;
#pragma unroll
        for (int j = 0; j < G / 64; ++j)
            s += part[vi * G + j * 64 + lane];
        s = wave_reduce(s);
        if (lane == 0) {
            if (vi < NPAIR) Stri[vi]         = s;
            else            Ssum[vi - NPAIR] = s;
        }
    }
    __syncthreads();

    // 2) Augmented matrix [cov | I]
    {
        const int d = tid >> 4, e = tid & 15;
        const int lo = d < e ? d : e, hi = d < e ? e : d;
        const float invN = 1.0f / (float)NTOT;
        const float cov = (Stri[tri_idx(lo, hi)] -
                           Ssum[d] * Ssum[e] * invN) /
                          (float)(NTOT - 1);
        A[d][e]     = cov;
        A[d][D + e] = (d == e) ? 1.0f : 0.0f;
    }
    __syncthreads();

    // 3) Gauss-Jordan (no pivoting; cov ~ 0.01*I, well-conditioned).
    const int r0 = tid >> 5;   // 0..7
    const int c0 = tid & 31;   // 0..31
    const int r1 = r0 + 8;
    for (int k = 0; k < D; ++k) {
        const float pivinv = 1.0f / A[k][k];
        __syncthreads();
        if (tid < 32) A[k][tid] *= pivinv;
        __syncthreads();
        const float f0 = A[r0][k];
        const float f1 = A[r1][k];
        __syncthreads();
        const float akc = A[k][c0];
        if (r0 != k) A[r0][c0] -= f0 * akc;
        if (r1 != k) A[r1][c0] -= f1 * akc;
        __syncthreads();
    }

    // 4) result = (1/N) * sum_{d,e} P[d][e] * S[d][e]
    float term;
    {
        const int d = tid >> 4, e = tid & 15;
        const int lo = d < e ? d : e, hi = d < e ? e : d;
        float p = A[d][D + e];
        const float scale = 1.0f;  // OFF_DIAGONAL_SCALE
        if (d != e) p *= scale;
        term = p * Stri[tri_idx(lo, hi)];
    }
    term = wave_reduce(term);

    __shared__ float wsum[4];
    if (lane == 0) wsum[wv] = term;
    __syncthreads();
    if (tid == 0) {
        const float tot = (wsum[0] + wsum[1]) + (wsum[2] + wsum[3]);
        out[0] = tot / (float)NTOT;
    }
}

extern "C" void kernel_launch(void* const* d_in, const int* in_sizes, int n_in,
                              void* d_out, int out_size, void* d_ws, size_t ws_size,
                              hipStream_t stream) {
    const float* y_true = (const float*)d_in[0];
    const float* y_pred = (const float*)d_in[1];
    float* out  = (float*)d_out;
    float* part = (float*)d_ws;   // needs NVALS * G * 4 = 1,050,624 bytes

    hipLaunchKernelGGL(gram_partial, dim3(G), dim3(256), 0, stream,
                       y_true, y_pred, part);
    hipLaunchKernelGGL(finalize_kernel, dim3(1), dim3(256), 0, stream,
                       part, out);
}

// Round 4
// 130.536 us; speedup vs baseline: 4.1201x; 4.1160x over previous
//
#include <hip/hip_runtime.h>

// Problem constants (B,V,T,H,W) = (32, 8, 2, 192, 288)
#define D        16        // V*T
#define NPAIR    136       // D*(D+1)/2 upper-triangle Gram entries
#define NVALS    152       // NPAIR + D row sums
#define HW       55296     // H*W
#define BSTRIDE  884736    // V*T*H*W (batch stride in floats)
#define NTOT     1769472   // B*H*W = N
#define TCOLS    256       // columns per LDS tile (16 KB tile)
#define TPB      4         // tiles per block
#define CPB      1024      // columns per block (HW % 1024 == 0 -> no batch crossing)
#define BPP      54        // blocks per batch-plane (HW / CPB)
#define G        1728      // grid = NTOT / CPB
#define GJ       27        // G / 64 (finalize loads per lane)

__device__ __forceinline__ float wave_reduce(float x) {
    x += __shfl_down(x, 32);
    x += __shfl_down(x, 16);
    x += __shfl_down(x, 8);
    x += __shfl_down(x, 4);
    x += __shfl_down(x, 2);
    x += __shfl_down(x, 1);
    return x;
}

__host__ __device__ constexpr int tri_idx(int d, int e) {
    // d <= e required
    return d * D - (d * (d - 1)) / 2 + (e - d);
}

// Wave W owns rows {2W, 2W+1, 14-2W, 15-2W} -> exactly 34 pairs each.
// Residual tile lives in LDS; each lane consumes ONE column at a time so
// per-thread live state is ~34 accs + <=16 column values. All indices are
// compile-time (round-2/3 lesson: anything less spills to scratch).
// All 4 waves execute identical barrier counts (switch is wave-uniform).
template<int W>
__device__ __forceinline__ void gram_wave(const float* __restrict__ bt,
                                          const float* __restrict__ bp,
                                          float (*tile)[TCOLS],
                                          float* __restrict__ part,
                                          int blk, int tid) {
    constexpr int R0 = 2 * W;        // min row this wave touches
    constexpr int R1 = 2 * W + 1;
    constexpr int R2 = 14 - 2 * W;
    constexpr int R3 = 15 - 2 * W;

    float accA[D - R0];
    float accB[D - R1];
    float accC[D - R2];
    float accD[D - R3];
    float sA = 0.0f, sB = 0.0f, sC = 0.0f, sD = 0.0f;
#pragma unroll
    for (int j = 0; j < D - R0; ++j) accA[j] = 0.0f;
#pragma unroll
    for (int j = 0; j < D - R1; ++j) accB[j] = 0.0f;
#pragma unroll
    for (int j = 0; j < D - R2; ++j) accC[j] = 0.0f;
#pragma unroll
    for (int j = 0; j < D - R3; ++j) accD[j] = 0.0f;

    const int lane = tid & 63;
    const int wid  = tid >> 6;

    for (int t = 0; t < TPB; ++t) {
        const float* tt = bt + t * TCOLS;
        const float* tp = bp + t * TCOLS;
        __syncthreads();   // prior tile's compute reads are done
        // Stage: 4 steps x 4 waves = 16 rows; float4-coalesced, residual
        // computed in-flight. One global byte read exactly once.
#pragma unroll
        for (int s = 0; s < 4; ++s) {
            const int row = s * 4 + wid;
            const float4 a = *reinterpret_cast<const float4*>(tt + row * HW + lane * 4);
            const float4 p = *reinterpret_cast<const float4*>(tp + row * HW + lane * 4);
            float4 r = make_float4(a.x - p.x, a.y - p.y, a.z - p.z, a.w - p.w);
            *reinterpret_cast<float4*>(&tile[row][lane * 4]) = r;
        }
        __syncthreads();
        // Compute: lane handles columns j*64+lane; consecutive lanes read
        // consecutive LDS words -> 2 lanes/bank (free on CDNA4).
#pragma unroll
        for (int j = 0; j < TCOLS / 64; ++j) {
            const int col = j * 64 + lane;
            float rv[D];
#pragma unroll
            for (int d = R0; d < D; ++d) rv[d] = tile[d][col];
#pragma unroll
            for (int e = R0; e < D; ++e) accA[e - R0] += rv[R0] * rv[e];
#pragma unroll
            for (int e = R1; e < D; ++e) accB[e - R1] += rv[R1] * rv[e];
#pragma unroll
            for (int e = R2; e < D; ++e) accC[e - R2] += rv[R2] * rv[e];
#pragma unroll
            for (int e = R3; e < D; ++e) accD[e - R3] += rv[R3] * rv[e];
            sA += rv[R0]; sB += rv[R1]; sC += rv[R2]; sD += rv[R3];
        }
    }

    // Epilogue: per-wave shuffle reduce; sets disjoint -> no cross-wave work.
#pragma unroll
    for (int e = R0; e < D; ++e) {
        const float v = wave_reduce(accA[e - R0]);
        if (lane == 0) part[tri_idx(R0, e) * G + blk] = v;
    }
#pragma unroll
    for (int e = R1; e < D; ++e) {
        const float v = wave_reduce(accB[e - R1]);
        if (lane == 0) part[tri_idx(R1, e) * G + blk] = v;
    }
#pragma unroll
    for (int e = R2; e < D; ++e) {
        const float v = wave_reduce(accC[e - R2]);
        if (lane == 0) part[tri_idx(R2, e) * G + blk] = v;
    }
#pragma unroll
    for (int e = R3; e < D; ++e) {
        const float v = wave_reduce(accD[e - R3]);
        if (lane == 0) part[tri_idx(R3, e) * G + blk] = v;
    }
    {
        float v;
        v = wave_reduce(sA); if (lane == 0) part[(NPAIR + R0) * G + blk] = v;
        v = wave_reduce(sB); if (lane == 0) part[(NPAIR + R1) * G + blk] = v;
        v = wave_reduce(sC); if (lane == 0) part[(NPAIR + R2) * G + blk] = v;
        v = wave_reduce(sD); if (lane == 0) part[(NPAIR + R3) * G + blk] = v;
    }
}

__global__ __launch_bounds__(256)
void gram_partial(const float* __restrict__ yt, const float* __restrict__ yp,
                  float* __restrict__ part) {
    __shared__ float tile[D][TCOLS];   // 16 KB
    const int tid = threadIdx.x;
    const int b   = blockIdx.x / BPP;
    const int hw0 = (blockIdx.x - b * BPP) * CPB;
    const float* bt = yt + (size_t)b * BSTRIDE + hw0;
    const float* bp = yp + (size_t)b * BSTRIDE + hw0;
    switch (tid >> 6) {
        case 0:  gram_wave<0>(bt, bp, tile, part, blockIdx.x, tid); break;
        case 1:  gram_wave<1>(bt, bp, tile, part, blockIdx.x, tid); break;
        case 2:  gram_wave<2>(bt, bp, tile, part, blockIdx.x, tid); break;
        default: gram_wave<3>(bt, bp, tile, part, blockIdx.x, tid); break;
    }
}

// Pass 2 (single block, 256 threads): reduce partials, build cov, invert
// 16x16 via cooperative Gauss-Jordan, emit (1/N) * sum(P .* S).
__global__ void finalize_kernel(const float* __restrict__ part,
                                float* __restrict__ out) {
    __shared__ float Stri[NPAIR];
    __shared__ float Ssum[D];
    __shared__ float A[D][2 * D + 1];   // [cov | I], padded row

    const int tid  = threadIdx.x;
    const int lane = tid & 63;
    const int wv   = tid >> 6;

    // 1) Reduce G block-partials per value: one wave per value row.
    for (int vi = wv; vi < NVALS; vi += 4) {
        float s = 0.0f;
#pragma unroll
        for (int j = 0; j < GJ; ++j)
            s += part[vi * G + j * 64 + lane];
        s = wave_reduce(s);
        if (lane == 0) {
            if (vi < NPAIR) Stri[vi]         = s;
            else            Ssum[vi - NPAIR] = s;
        }
    }
    __syncthreads();

    // 2) Augmented matrix [cov | I]
    {
        const int d = tid >> 4, e = tid & 15;
        const int lo = d < e ? d : e, hi = d < e ? e : d;
        const float invN = 1.0f / (float)NTOT;
        const float cov = (Stri[tri_idx(lo, hi)] -
                           Ssum[d] * Ssum[e] * invN) /
                          (float)(NTOT - 1);
        A[d][e]     = cov;
        A[d][D + e] = (d == e) ? 1.0f : 0.0f;
    }
    __syncthreads();

    // 3) Gauss-Jordan (no pivoting; cov ~ 0.01*I, well-conditioned).
    const int r0 = tid >> 5;   // 0..7
    const int c0 = tid & 31;   // 0..31
    const int r1 = r0 + 8;
    for (int k = 0; k < D; ++k) {
        const float pivinv = 1.0f / A[k][k];
        __syncthreads();
        if (tid < 32) A[k][tid] *= pivinv;
        __syncthreads();
        const float f0 = A[r0][k];
        const float f1 = A[r1][k];
        __syncthreads();
        const float akc = A[k][c0];
        if (r0 != k) A[r0][c0] -= f0 * akc;
        if (r1 != k) A[r1][c0] -= f1 * akc;
        __syncthreads();
    }

    // 4) result = (1/N) * sum_{d,e} P[d][e] * S[d][e]
    float term;
    {
        const int d = tid >> 4, e = tid & 15;
        const int lo = d < e ? d : e, hi = d < e ? e : d;
        float p = A[d][D + e];
        const float scale = 1.0f;  // OFF_DIAGONAL_SCALE
        if (d != e) p *= scale;
        term = p * Stri[tri_idx(lo, hi)];
    }
    term = wave_reduce(term);

    __shared__ float wsum[4];
    if (lane == 0) wsum[wv] = term;
    __syncthreads();
    if (tid == 0) {
        const float tot = (wsum[0] + wsum[1]) + (wsum[2] + wsum[3]);
        out[0] = tot / (float)NTOT;
    }
}

extern "C" void kernel_launch(void* const* d_in, const int* in_sizes, int n_in,
                              void* d_out, int out_size, void* d_ws, size_t ws_size,
                              hipStream_t stream) {
    const float* y_true = (const float*)d_in[0];
    const float* y_pred = (const float*)d_in[1];
    float* out  = (float*)d_out;
    float* part = (float*)d_ws;   // needs NVALS * G * 4 = 1,050,624 bytes

    hipLaunchKernelGGL(gram_partial, dim3(G), dim3(256), 0, stream,
                       y_true, y_pred, part);
    hipLaunchKernelGGL(finalize_kernel, dim3(1), dim3(256), 0, stream,
                       part, out);
}